// Round 1
// baseline (2083.663 us; speedup 1.0000x reference)
//
#include <hip/hip_runtime.h>

// SidNet signed diffusion: K=10 layers of
//   newP = Ap@P + Am@M + 0.15*X ; newM = Am@P + Ap@M
// Strategy: build CSR (row-major) for both COO adjacencies once per call,
// then one wave owns one output row (64 lanes x float2 = 512B = D*4B),
// register-accumulating both newP and newM -> no atomics in the hot loop.

#define TB 256

__global__ void zero_int_kernel(int* __restrict__ p, int n) {
    int i = blockIdx.x * blockDim.x + threadIdx.x;
    if (i < n) p[i] = 0;
}

__global__ void copy_int_kernel(const int* __restrict__ src, int* __restrict__ dst, int n) {
    int i = blockIdx.x * blockDim.x + threadIdx.x;
    if (i < n) dst[i] = src[i];
}

__global__ void hist_kernel(const int* __restrict__ rows, int E, int* __restrict__ cnt) {
    int e = blockIdx.x * blockDim.x + threadIdx.x;
    if (e < E) atomicAdd(&cnt[rows[e]], 1);
}

// One-block exclusive scan over n counters -> off[0..n], off[0]=0, off[n]=total.
// Wave-shuffle inclusive scans; few barriers per 1024-tile.
__global__ void exscan_kernel(const int* __restrict__ cnt, int* __restrict__ off, int n) {
    __shared__ int wsum[16];
    __shared__ int sbase;
    int tid = threadIdx.x;
    int lane = tid & 63, wid = tid >> 6;
    if (tid == 0) sbase = 0;
    __syncthreads();
    int ntiles = (n + 1023) / 1024;
    for (int t = 0; t < ntiles; ++t) {
        int i = t * 1024 + tid;
        int x = (i < n) ? cnt[i] : 0;
        int incl = x;
#pragma unroll
        for (int o = 1; o < 64; o <<= 1) {
            int y = __shfl_up(incl, o);
            if (lane >= o) incl += y;
        }
        if (lane == 63) wsum[wid] = incl;
        __syncthreads();
        if (wid == 0) {
            int s = (lane < 16) ? wsum[lane] : 0;
#pragma unroll
            for (int o = 1; o < 16; o <<= 1) {
                int y = __shfl_up(s, o);
                if (lane >= o) s += y;
            }
            if (lane < 16) wsum[lane] = s;
        }
        __syncthreads();
        int base = sbase + ((wid > 0) ? wsum[wid - 1] : 0);
        if (i < n) off[i + 1] = base + incl;
        int tile_total = wsum[15];
        __syncthreads();          // all sbase reads done before update
        if (tid == 0) sbase += tile_total;
        __syncthreads();          // update visible for next tile
    }
    if (tid == 0) off[0] = 0;
}

__global__ void fill_kernel(const int* __restrict__ rows, const int* __restrict__ cols,
                            const float* __restrict__ vals, int E,
                            int* __restrict__ cur, int* __restrict__ ccol,
                            float* __restrict__ cval) {
    int e = blockIdx.x * blockDim.x + threadIdx.x;
    if (e < E) {
        int r = rows[e];
        int p = atomicAdd(&cur[r], 1);
        ccol[p] = cols[e];
        cval[p] = vals[e];
    }
}

// One wave per row. lane handles feature dims [2*lane, 2*lane+1] as float2.
// Each gathered neighbor row (P[c], M[c]) feeds BOTH accumulators.
__global__ __launch_bounds__(TB) void layer_kernel(
    const int* __restrict__ offp, const int* __restrict__ colp, const float* __restrict__ valp,
    const int* __restrict__ offm, const int* __restrict__ colm, const float* __restrict__ valm,
    const float* __restrict__ P, const float* __restrict__ M,
    const float* __restrict__ X, float* __restrict__ nP, float* __restrict__ nM, int N) {
    int row = blockIdx.x * (TB / 64) + (threadIdx.x >> 6);
    if (row >= N) return;
    int lane = threadIdx.x & 63;
    const float2* __restrict__ P2 = (const float2*)P;
    const float2* __restrict__ M2 = (const float2*)M;
    const float2* __restrict__ X2 = (const float2*)X;
    int ridx = row * 64 + lane;

    float2 x = X2[ridx];
    float2 aP = make_float2(0.15f * x.x, 0.15f * x.y);
    float2 aM = make_float2(0.0f, 0.0f);

    int b0 = offp[row], e0 = offp[row + 1];
    for (int j = b0; j < e0; ++j) {
        int c = colp[j];
        float v = valp[j];
        float2 pc = P2[c * 64 + lane];
        float2 mc = M2[c * 64 + lane];
        aP.x += v * pc.x; aP.y += v * pc.y;
        aM.x += v * mc.x; aM.y += v * mc.y;
    }
    int b1 = offm[row], e1 = offm[row + 1];
    for (int j = b1; j < e1; ++j) {
        int c = colm[j];
        float v = valm[j];
        float2 pc = P2[c * 64 + lane];
        float2 mc = M2[c * 64 + lane];
        aP.x += v * mc.x; aP.y += v * mc.y;
        aM.x += v * pc.x; aM.y += v * pc.y;
    }
    ((float2*)nP)[ridx] = aP;
    ((float2*)nM)[ridx] = aM;
}

extern "C" void kernel_launch(void* const* d_in, const int* in_sizes, int n_in,
                              void* d_out, int out_size, void* d_ws, size_t ws_size,
                              hipStream_t stream) {
    const int*   rows_p = (const int*)d_in[0];
    const int*   cols_p = (const int*)d_in[1];
    const float* vals_p = (const float*)d_in[2];
    const int*   rows_m = (const int*)d_in[3];
    const int*   cols_m = (const int*)d_in[4];
    const float* vals_m = (const float*)d_in[5];
    const float* X      = (const float*)d_in[6];
    const float* M0     = (const float*)d_in[7];

    const int E = in_sizes[0];
    const int D = 128;
    const int N = in_sizes[6] / D;
    const int K = 10;

    float* outP = (float*)d_out;
    float* outM = outP + (size_t)N * D;

    // Workspace carve-up (~62 MB total).
    char* ws = (char*)d_ws;
    size_t o = 0;
    auto alloc = [&](size_t b) -> void* {
        void* p = ws + o;
        o += (b + 255) & ~(size_t)255;
        return p;
    };
    float* BP    = (float*)alloc((size_t)N * D * sizeof(float));
    float* BM    = (float*)alloc((size_t)N * D * sizeof(float));
    int*   cnt_p = (int*)alloc((size_t)N * sizeof(int));
    int*   cnt_m = (int*)alloc((size_t)N * sizeof(int));
    int*   off_p = (int*)alloc((size_t)(N + 1) * sizeof(int));
    int*   off_m = (int*)alloc((size_t)(N + 1) * sizeof(int));
    int*   cur_p = (int*)alloc((size_t)N * sizeof(int));
    int*   cur_m = (int*)alloc((size_t)N * sizeof(int));
    int*   col_p = (int*)alloc((size_t)E * sizeof(int));
    float* val_p = (float*)alloc((size_t)E * sizeof(float));
    int*   col_m = (int*)alloc((size_t)E * sizeof(int));
    float* val_m = (float*)alloc((size_t)E * sizeof(float));

    int gN = (N + TB - 1) / TB;
    int gE = (E + TB - 1) / TB;

    // --- build CSR for both adjacencies ---
    zero_int_kernel<<<gN, TB, 0, stream>>>(cnt_p, N);
    zero_int_kernel<<<gN, TB, 0, stream>>>(cnt_m, N);
    hist_kernel<<<gE, TB, 0, stream>>>(rows_p, E, cnt_p);
    hist_kernel<<<gE, TB, 0, stream>>>(rows_m, E, cnt_m);
    exscan_kernel<<<1, 1024, 0, stream>>>(cnt_p, off_p, N);
    exscan_kernel<<<1, 1024, 0, stream>>>(cnt_m, off_m, N);
    copy_int_kernel<<<gN, TB, 0, stream>>>(off_p, cur_p, N);
    copy_int_kernel<<<gN, TB, 0, stream>>>(off_m, cur_m, N);
    fill_kernel<<<gE, TB, 0, stream>>>(rows_p, cols_p, vals_p, E, cur_p, col_p, val_p);
    fill_kernel<<<gE, TB, 0, stream>>>(rows_m, cols_m, vals_m, E, cur_m, col_m, val_m);

    // --- K diffusion layers, ping-pong; odd k writes d_out, k=9 final ---
    const float* Pcur = X;
    const float* Mcur = M0;
    int gRows = (N + (TB / 64) - 1) / (TB / 64);
    for (int k = 0; k < K; ++k) {
        float* nP;
        float* nM;
        if ((k & 1) == 0) { nP = BP;   nM = BM;   }
        else              { nP = outP; nM = outM; }
        layer_kernel<<<gRows, TB, 0, stream>>>(off_p, col_p, val_p,
                                               off_m, col_m, val_m,
                                               Pcur, Mcur, X, nP, nM, N);
        Pcur = nP;
        Mcur = nM;
    }
}

// Round 3
// 1878.636 us; speedup vs baseline: 1.1091x; 1.1091x over previous
//
#include <hip/hip_runtime.h>
#include <math.h>

// SidNet signed diffusion, S/D-decoupled form:
//   S=P+M, D=P-M:  S' = (Ap+Am)@S + cX ;  D' = (Ap-Am)@D + cX
// Merged CSR (2E edges) with ONE signed value array: val = +v for Ap edges,
// -v for Am edges (input vals are >= 0, so S-system uses fabsf(val)).
// One wave per (row, system); 64 lanes x float2 = 512B row. Gather loop
// unrolled x4 for memory-level parallelism. No atomics in the hot loop.

#define TB 256

__global__ void zero_int_kernel(int* __restrict__ p, int n) {
    int i = blockIdx.x * blockDim.x + threadIdx.x;
    if (i < n) p[i] = 0;
}

__global__ void copy_int_kernel(const int* __restrict__ src, int* __restrict__ dst, int n) {
    int i = blockIdx.x * blockDim.x + threadIdx.x;
    if (i < n) dst[i] = src[i];
}

__global__ void hist_kernel(const int* __restrict__ rows, int E, int* __restrict__ cnt) {
    int e = blockIdx.x * blockDim.x + threadIdx.x;
    if (e < E) atomicAdd(&cnt[rows[e]], 1);
}

// --- 3-phase parallel exclusive scan over cnt[0..n) -> off[0..n] ---
// NOTE: shuffles are issued UNCONDITIONALLY (convergent op) — the
// conditional-ternary form reads undefined data from exec-masked lanes.
__global__ void scanA_kernel(const int* __restrict__ cnt, int* __restrict__ bsum, int n) {
    __shared__ int wsum[16];
    int tid = threadIdx.x, lane = tid & 63, wid = tid >> 6;
    int i = blockIdx.x * 1024 + tid;
    int x = (i < n) ? cnt[i] : 0;
#pragma unroll
    for (int o = 1; o < 64; o <<= 1) { int y = __shfl_up(x, o); if (lane >= o) x += y; }
    if (lane == 63) wsum[wid] = x;
    __syncthreads();
    if (tid == 0) {
        int s = 0;
#pragma unroll
        for (int w = 0; w < 16; ++w) s += wsum[w];
        bsum[blockIdx.x] = s;
    }
}

// single block: exclusive scan of bsum[0..nb) in place (nb <= 1024)
__global__ void scanB_kernel(int* __restrict__ bsum, int nb) {
    __shared__ int wsum[16];
    int tid = threadIdx.x, lane = tid & 63, wid = tid >> 6;
    int x = (tid < nb) ? bsum[tid] : 0;
    int incl = x;
#pragma unroll
    for (int o = 1; o < 64; o <<= 1) { int y = __shfl_up(incl, o); if (lane >= o) incl += y; }
    if (lane == 63) wsum[wid] = incl;
    __syncthreads();
    if (wid == 0) {
        int s = (lane < 16) ? wsum[lane] : 0;
#pragma unroll
        for (int o = 1; o < 16; o <<= 1) { int y = __shfl_up(s, o); if (lane >= o) s += y; }
        if (lane < 16) wsum[lane] = s;
    }
    __syncthreads();
    int base = (wid > 0) ? wsum[wid - 1] : 0;
    if (tid < nb) bsum[tid] = base + incl - x;   // exclusive
}

__global__ void scanC_kernel(const int* __restrict__ cnt, const int* __restrict__ bsum,
                             int* __restrict__ off, int n) {
    __shared__ int wsum[16];
    int tid = threadIdx.x, lane = tid & 63, wid = tid >> 6;
    int i = blockIdx.x * 1024 + tid;
    int x = (i < n) ? cnt[i] : 0;
    int incl = x;
#pragma unroll
    for (int o = 1; o < 64; o <<= 1) { int y = __shfl_up(incl, o); if (lane >= o) incl += y; }
    if (lane == 63) wsum[wid] = incl;
    __syncthreads();
    if (wid == 0) {
        int s = (lane < 16) ? wsum[lane] : 0;
#pragma unroll
        for (int o = 1; o < 16; o <<= 1) { int y = __shfl_up(s, o); if (lane >= o) s += y; }
        if (lane < 16) wsum[lane] = s;
    }
    __syncthreads();
    int base = bsum[blockIdx.x] + ((wid > 0) ? wsum[wid - 1] : 0);
    if (i < n) {
        off[i] = base + incl - x;             // exclusive prefix
        if (i == n - 1) off[n] = base + incl; // total
    }
}

// Fill merged CSR with signed values: +v (plus adjacency), -v (minus).
__global__ void fill_kernel(const int* __restrict__ rows, const int* __restrict__ cols,
                            const float* __restrict__ vals, int E, float sgn,
                            int* __restrict__ cur, int* __restrict__ ccol,
                            float* __restrict__ cval) {
    int e = blockIdx.x * blockDim.x + threadIdx.x;
    if (e < E) {
        int r = rows[e];
        int p = atomicAdd(&cur[r], 1);
        ccol[p] = cols[e];
        cval[p] = sgn * vals[e];
    }
}

// S0 = X + M0, D0 = X - M0  (written to d_out region)
__global__ void init_kernel(const float* __restrict__ X, const float* __restrict__ M0,
                            float* __restrict__ S, float* __restrict__ D, int n) {
    int i = blockIdx.x * blockDim.x + threadIdx.x;
    if (i < n) {
        float x = X[i], m = M0[i];
        S[i] = x + m;
        D[i] = x - m;
    }
}

// P = (S+D)/2, M = (S-D)/2, in place over d_out
__global__ void final_kernel(float* __restrict__ S, float* __restrict__ D, int n) {
    int i = blockIdx.x * blockDim.x + threadIdx.x;
    if (i < n) {
        float s = S[i], d = D[i];
        S[i] = 0.5f * (s + d);
        D[i] = 0.5f * (s - d);
    }
}

// One wave per (row, system). blockIdx.y = system (0:S, 1:D).
// S uses fabsf(val); D uses signed val.
__global__ __launch_bounds__(TB) void layer_kernel(
    const int* __restrict__ off, const int* __restrict__ col,
    const float* __restrict__ val,
    const float* __restrict__ Sin, const float* __restrict__ Din,
    float* __restrict__ Sout, float* __restrict__ Dout,
    const float* __restrict__ X, int N) {
    int row = blockIdx.x * (TB / 64) + (threadIdx.x >> 6);
    if (row >= N) return;
    int lane = threadIdx.x & 63;
    int sys = blockIdx.y;
    const float2* In2 = (const float2*)(sys ? Din : Sin);
    float2*       Out2 = (float2*)(sys ? Dout : Sout);
    const float2* X2 = (const float2*)X;

    int ridx = row * 64 + lane;
    float2 x = X2[ridx];
    float ax = 0.15f * x.x, ay = 0.15f * x.y;

    int b = off[row], e = off[row + 1];
    int j = b;
    for (; j + 4 <= e; j += 4) {
        int c0 = col[j], c1 = col[j + 1], c2 = col[j + 2], c3 = col[j + 3];
        float v0 = val[j], v1 = val[j + 1], v2 = val[j + 2], v3 = val[j + 3];
        if (!sys) { v0 = fabsf(v0); v1 = fabsf(v1); v2 = fabsf(v2); v3 = fabsf(v3); }
        float2 g0 = In2[c0 * 64 + lane];
        float2 g1 = In2[c1 * 64 + lane];
        float2 g2 = In2[c2 * 64 + lane];
        float2 g3 = In2[c3 * 64 + lane];
        ax += v0 * g0.x + v1 * g1.x + v2 * g2.x + v3 * g3.x;
        ay += v0 * g0.y + v1 * g1.y + v2 * g2.y + v3 * g3.y;
    }
    for (; j < e; ++j) {
        int c = col[j];
        float v = val[j];
        if (!sys) v = fabsf(v);
        float2 g = In2[c * 64 + lane];
        ax += v * g.x;
        ay += v * g.y;
    }
    Out2[ridx] = make_float2(ax, ay);
}

extern "C" void kernel_launch(void* const* d_in, const int* in_sizes, int n_in,
                              void* d_out, int out_size, void* d_ws, size_t ws_size,
                              hipStream_t stream) {
    const int*   rows_p = (const int*)d_in[0];
    const int*   cols_p = (const int*)d_in[1];
    const float* vals_p = (const float*)d_in[2];
    const int*   rows_m = (const int*)d_in[3];
    const int*   cols_m = (const int*)d_in[4];
    const float* vals_m = (const float*)d_in[5];
    const float* X      = (const float*)d_in[6];
    const float* M0     = (const float*)d_in[7];

    const int E = in_sizes[0];
    const int D = 128;
    const int N = in_sizes[6] / D;
    const int K = 10;
    const int E2 = 2 * E;
    const size_t ND = (size_t)N * D;

    float* outS = (float*)d_out;          // d_out doubles as one state pair
    float* outD = outS + ND;

    char* ws = (char*)d_ws;
    size_t o = 0;
    auto alloc = [&](size_t b) -> void* {
        void* p = ws + o;
        o += (b + 255) & ~(size_t)255;
        return p;
    };
    float* wsS  = (float*)alloc(ND * sizeof(float));
    float* wsD  = (float*)alloc(ND * sizeof(float));
    int*   cnt  = (int*)alloc((size_t)N * sizeof(int));
    int*   off  = (int*)alloc((size_t)(N + 1) * sizeof(int));
    int*   cur  = (int*)alloc((size_t)N * sizeof(int));
    int*   bsum = (int*)alloc(1024 * sizeof(int));
    int*   col  = (int*)alloc((size_t)E2 * sizeof(int));
    float* val  = (float*)alloc((size_t)E2 * sizeof(float));

    int gN  = (N + TB - 1) / TB;
    int gE  = (E + TB - 1) / TB;
    int gND = (int)((ND + TB - 1) / TB);
    int nb  = (N + 1023) / 1024;

    // --- build merged CSR ---
    zero_int_kernel<<<gN, TB, 0, stream>>>(cnt, N);
    hist_kernel<<<gE, TB, 0, stream>>>(rows_p, E, cnt);
    hist_kernel<<<gE, TB, 0, stream>>>(rows_m, E, cnt);
    scanA_kernel<<<nb, 1024, 0, stream>>>(cnt, bsum, N);
    scanB_kernel<<<1, 1024, 0, stream>>>(bsum, nb);
    scanC_kernel<<<nb, 1024, 0, stream>>>(cnt, bsum, off, N);
    copy_int_kernel<<<gN, TB, 0, stream>>>(off, cur, N);
    fill_kernel<<<gE, TB, 0, stream>>>(rows_p, cols_p, vals_p, E,  1.0f, cur, col, val);
    fill_kernel<<<gE, TB, 0, stream>>>(rows_m, cols_m, vals_m, E, -1.0f, cur, col, val);

    // --- init: (S0, D0) -> d_out ---
    init_kernel<<<gND, TB, 0, stream>>>(X, M0, outS, outD, (int)ND);

    // --- K layers; even k: out->ws, odd k: ws->out. k=9 ends in d_out. ---
    dim3 gL((N + (TB / 64) - 1) / (TB / 64), 2);
    const float* Sc = outS; const float* Dc = outD;
    for (int k = 0; k < K; ++k) {
        float *nS, *nD;
        if ((k & 1) == 0) { nS = wsS;  nD = wsD;  }
        else              { nS = outS; nD = outD; }
        layer_kernel<<<gL, TB, 0, stream>>>(off, col, val,
                                            Sc, Dc, nS, nD, X, N);
        Sc = nS; Dc = nD;
    }

    // --- finalize in place on d_out ---
    final_kernel<<<gND, TB, 0, stream>>>(outS, outD, (int)ND);
}

// Round 4
// 1189.754 us; speedup vs baseline: 1.7513x; 1.5790x over previous
//
#include <hip/hip_runtime.h>
#include <math.h>

// SidNet signed diffusion, S/D-decoupled + bf16 inter-layer state.
//   S=P+M, D=P-M:  S' = (Ap+Am)@S + cX ;  D' = (Ap-Am)@D + cX
// Merged CSR (2E edges), ONE signed value array (S-system uses fabsf).
// States stored as packed 2xbf16 per uint (row = 64 uints = 256B); all
// accumulation in fp32. One wave per (row, system), gather unrolled x4.

#define TB 256

__device__ __forceinline__ unsigned pack_bf16(float a, float b) {
    unsigned ua = __float_as_uint(a), ub = __float_as_uint(b);
    ua += 0x7fffu + ((ua >> 16) & 1u);   // RNE
    ub += 0x7fffu + ((ub >> 16) & 1u);
    return (ua >> 16) | (ub & 0xffff0000u);
}

__device__ __forceinline__ float2 unpack_bf16(unsigned w) {
    float2 r;
    r.x = __uint_as_float(w << 16);
    r.y = __uint_as_float(w & 0xffff0000u);
    return r;
}

__global__ void zero_int_kernel(int* __restrict__ p, int n) {
    int i = blockIdx.x * blockDim.x + threadIdx.x;
    if (i < n) p[i] = 0;
}

__global__ void copy_int_kernel(const int* __restrict__ src, int* __restrict__ dst, int n) {
    int i = blockIdx.x * blockDim.x + threadIdx.x;
    if (i < n) dst[i] = src[i];
}

__global__ void hist_kernel(const int* __restrict__ rows, int E, int* __restrict__ cnt) {
    int e = blockIdx.x * blockDim.x + threadIdx.x;
    if (e < E) atomicAdd(&cnt[rows[e]], 1);
}

// --- 3-phase parallel exclusive scan (safe unconditional shuffles) ---
__global__ void scanA_kernel(const int* __restrict__ cnt, int* __restrict__ bsum, int n) {
    __shared__ int wsum[16];
    int tid = threadIdx.x, lane = tid & 63, wid = tid >> 6;
    int i = blockIdx.x * 1024 + tid;
    int x = (i < n) ? cnt[i] : 0;
#pragma unroll
    for (int o = 1; o < 64; o <<= 1) { int y = __shfl_up(x, o); if (lane >= o) x += y; }
    if (lane == 63) wsum[wid] = x;
    __syncthreads();
    if (tid == 0) {
        int s = 0;
#pragma unroll
        for (int w = 0; w < 16; ++w) s += wsum[w];
        bsum[blockIdx.x] = s;
    }
}

__global__ void scanB_kernel(int* __restrict__ bsum, int nb) {
    __shared__ int wsum[16];
    int tid = threadIdx.x, lane = tid & 63, wid = tid >> 6;
    int x = (tid < nb) ? bsum[tid] : 0;
    int incl = x;
#pragma unroll
    for (int o = 1; o < 64; o <<= 1) { int y = __shfl_up(incl, o); if (lane >= o) incl += y; }
    if (lane == 63) wsum[wid] = incl;
    __syncthreads();
    if (wid == 0) {
        int s = (lane < 16) ? wsum[lane] : 0;
#pragma unroll
        for (int o = 1; o < 16; o <<= 1) { int y = __shfl_up(s, o); if (lane >= o) s += y; }
        if (lane < 16) wsum[lane] = s;
    }
    __syncthreads();
    int base = (wid > 0) ? wsum[wid - 1] : 0;
    if (tid < nb) bsum[tid] = base + incl - x;
}

__global__ void scanC_kernel(const int* __restrict__ cnt, const int* __restrict__ bsum,
                             int* __restrict__ off, int n) {
    __shared__ int wsum[16];
    int tid = threadIdx.x, lane = tid & 63, wid = tid >> 6;
    int i = blockIdx.x * 1024 + tid;
    int x = (i < n) ? cnt[i] : 0;
    int incl = x;
#pragma unroll
    for (int o = 1; o < 64; o <<= 1) { int y = __shfl_up(incl, o); if (lane >= o) incl += y; }
    if (lane == 63) wsum[wid] = incl;
    __syncthreads();
    if (wid == 0) {
        int s = (lane < 16) ? wsum[lane] : 0;
#pragma unroll
        for (int o = 1; o < 16; o <<= 1) { int y = __shfl_up(s, o); if (lane >= o) s += y; }
        if (lane < 16) wsum[lane] = s;
    }
    __syncthreads();
    int base = bsum[blockIdx.x] + ((wid > 0) ? wsum[wid - 1] : 0);
    if (i < n) {
        off[i] = base + incl - x;
        if (i == n - 1) off[n] = base + incl;
    }
}

__global__ void fill_kernel(const int* __restrict__ rows, const int* __restrict__ cols,
                            const float* __restrict__ vals, int E, float sgn,
                            int* __restrict__ cur, int* __restrict__ ccol,
                            float* __restrict__ cval) {
    int e = blockIdx.x * blockDim.x + threadIdx.x;
    if (e < E) {
        int r = rows[e];
        int p = atomicAdd(&cur[r], 1);
        ccol[p] = cols[e];
        cval[p] = sgn * vals[e];
    }
}

// Sb = bf16(X+M0), Db = bf16(X-M0), tXb = bf16(0.15*X). n = ND/2 pairs.
__global__ void init_kernel(const float* __restrict__ X, const float* __restrict__ M0,
                            unsigned* __restrict__ Sb, unsigned* __restrict__ Db,
                            unsigned* __restrict__ tXb, int n) {
    int i = blockIdx.x * blockDim.x + threadIdx.x;
    if (i < n) {
        float2 x = ((const float2*)X)[i];
        float2 m = ((const float2*)M0)[i];
        Sb[i]  = pack_bf16(x.x + m.x, x.y + m.y);
        Db[i]  = pack_bf16(x.x - m.x, x.y - m.y);
        tXb[i] = pack_bf16(0.15f * x.x, 0.15f * x.y);
    }
}

// P = (S+D)/2, M = (S-D)/2 -> fp32 d_out. n = ND/2 pairs.
__global__ void final_kernel(const unsigned* __restrict__ Sb, const unsigned* __restrict__ Db,
                             float* __restrict__ P, float* __restrict__ M, int n) {
    int i = blockIdx.x * blockDim.x + threadIdx.x;
    if (i < n) {
        float2 s = unpack_bf16(Sb[i]);
        float2 d = unpack_bf16(Db[i]);
        ((float2*)P)[i] = make_float2(0.5f * (s.x + d.x), 0.5f * (s.y + d.y));
        ((float2*)M)[i] = make_float2(0.5f * (s.x - d.x), 0.5f * (s.y - d.y));
    }
}

// One wave per (row, system). blockIdx.y = system (0:S uses fabsf(val), 1:D).
__global__ __launch_bounds__(TB) void layer_kernel(
    const int* __restrict__ off, const int* __restrict__ col,
    const float* __restrict__ val,
    const unsigned* __restrict__ Sin, const unsigned* __restrict__ Din,
    unsigned* __restrict__ Sout, unsigned* __restrict__ Dout,
    const unsigned* __restrict__ tXb, int N) {
    int row = blockIdx.x * (TB / 64) + (threadIdx.x >> 6);
    if (row >= N) return;
    int lane = threadIdx.x & 63;
    int sys = blockIdx.y;
    const unsigned* __restrict__ In  = sys ? Din : Sin;
    unsigned* __restrict__       Out = sys ? Dout : Sout;

    int ridx = row * 64 + lane;
    float2 t = unpack_bf16(tXb[ridx]);
    float ax = t.x, ay = t.y;

    int b = off[row], e = off[row + 1];
    int j = b;
    for (; j + 4 <= e; j += 4) {
        int c0 = col[j], c1 = col[j + 1], c2 = col[j + 2], c3 = col[j + 3];
        float v0 = val[j], v1 = val[j + 1], v2 = val[j + 2], v3 = val[j + 3];
        if (!sys) { v0 = fabsf(v0); v1 = fabsf(v1); v2 = fabsf(v2); v3 = fabsf(v3); }
        unsigned w0 = In[c0 * 64 + lane];
        unsigned w1 = In[c1 * 64 + lane];
        unsigned w2 = In[c2 * 64 + lane];
        unsigned w3 = In[c3 * 64 + lane];
        float2 g0 = unpack_bf16(w0), g1 = unpack_bf16(w1);
        float2 g2 = unpack_bf16(w2), g3 = unpack_bf16(w3);
        ax += v0 * g0.x + v1 * g1.x + v2 * g2.x + v3 * g3.x;
        ay += v0 * g0.y + v1 * g1.y + v2 * g2.y + v3 * g3.y;
    }
    for (; j < e; ++j) {
        int c = col[j];
        float v = val[j];
        if (!sys) v = fabsf(v);
        float2 g = unpack_bf16(In[c * 64 + lane]);
        ax += v * g.x;
        ay += v * g.y;
    }
    Out[ridx] = pack_bf16(ax, ay);
}

extern "C" void kernel_launch(void* const* d_in, const int* in_sizes, int n_in,
                              void* d_out, int out_size, void* d_ws, size_t ws_size,
                              hipStream_t stream) {
    const int*   rows_p = (const int*)d_in[0];
    const int*   cols_p = (const int*)d_in[1];
    const float* vals_p = (const float*)d_in[2];
    const int*   rows_m = (const int*)d_in[3];
    const int*   cols_m = (const int*)d_in[4];
    const float* vals_m = (const float*)d_in[5];
    const float* X      = (const float*)d_in[6];
    const float* M0     = (const float*)d_in[7];

    const int E = in_sizes[0];
    const int D = 128;
    const int N = in_sizes[6] / D;
    const int K = 10;
    const int E2 = 2 * E;
    const size_t ND = (size_t)N * D;
    const int NP = (int)(ND / 2);   // packed pairs

    float* outP = (float*)d_out;
    float* outM = outP + ND;

    char* ws = (char*)d_ws;
    size_t o = 0;
    auto alloc = [&](size_t b) -> void* {
        void* p = ws + o;
        o += (b + 255) & ~(size_t)255;
        return p;
    };
    unsigned* SbA = (unsigned*)alloc((size_t)NP * 4);
    unsigned* DbA = (unsigned*)alloc((size_t)NP * 4);
    unsigned* SbB = (unsigned*)alloc((size_t)NP * 4);
    unsigned* DbB = (unsigned*)alloc((size_t)NP * 4);
    unsigned* tXb = (unsigned*)alloc((size_t)NP * 4);
    int*   cnt  = (int*)alloc((size_t)N * sizeof(int));
    int*   off  = (int*)alloc((size_t)(N + 1) * sizeof(int));
    int*   cur  = (int*)alloc((size_t)N * sizeof(int));
    int*   bsum = (int*)alloc(1024 * sizeof(int));
    int*   col  = (int*)alloc((size_t)E2 * sizeof(int));
    float* val  = (float*)alloc((size_t)E2 * sizeof(float));

    int gN  = (N + TB - 1) / TB;
    int gE  = (E + TB - 1) / TB;
    int gNP = (NP + TB - 1) / TB;
    int nb  = (N + 1023) / 1024;

    // --- build merged CSR ---
    zero_int_kernel<<<gN, TB, 0, stream>>>(cnt, N);
    hist_kernel<<<gE, TB, 0, stream>>>(rows_p, E, cnt);
    hist_kernel<<<gE, TB, 0, stream>>>(rows_m, E, cnt);
    scanA_kernel<<<nb, 1024, 0, stream>>>(cnt, bsum, N);
    scanB_kernel<<<1, 1024, 0, stream>>>(bsum, nb);
    scanC_kernel<<<nb, 1024, 0, stream>>>(cnt, bsum, off, N);
    copy_int_kernel<<<gN, TB, 0, stream>>>(off, cur, N);
    fill_kernel<<<gE, TB, 0, stream>>>(rows_p, cols_p, vals_p, E,  1.0f, cur, col, val);
    fill_kernel<<<gE, TB, 0, stream>>>(rows_m, cols_m, vals_m, E, -1.0f, cur, col, val);

    // --- init bf16 states ---
    init_kernel<<<gNP, TB, 0, stream>>>(X, M0, SbA, DbA, tXb, NP);

    // --- K layers, ping-pong A<->B; K even -> final state lands in A ---
    dim3 gL((N + (TB / 64) - 1) / (TB / 64), 2);
    unsigned *Si = SbA, *Di = DbA, *So = SbB, *Do = DbB;
    for (int k = 0; k < K; ++k) {
        layer_kernel<<<gL, TB, 0, stream>>>(off, col, val, Si, Di, So, Do, tXb, N);
        unsigned* t;
        t = Si; Si = So; So = t;
        t = Di; Di = Do; Do = t;
    }

    // --- unpack to fp32 outputs ---
    final_kernel<<<gNP, TB, 0, stream>>>(Si, Di, outP, outM, NP);
}

// Round 5
// 1157.839 us; speedup vs baseline: 1.7996x; 1.0276x over previous
//
#include <hip/hip_runtime.h>
#include <math.h>

// SidNet signed diffusion, S/D-decoupled + bf16 inter-layer state.
//   S=P+M, D=P-M:  S' = (Ap+Am)@S + cX ;  D' = (Ap-Am)@D + cX
// Merged CSR (2E edges) with packed (col, signed val) int2 edges.
// States packed 2xbf16/uint (row = 64 uints = 256B); fp32 accumulate.
// 1D grid, XCD-partition swizzle: S-blocks -> XCDs 0-3, D-blocks -> 4-7
// (id%8 round-robin heuristic), so each XCD's L2 caches ONE system (12.8MB).
// Gather loop unrolled x8 for MLP.

#define TB 256

__device__ __forceinline__ unsigned pack_bf16(float a, float b) {
    unsigned ua = __float_as_uint(a), ub = __float_as_uint(b);
    ua += 0x7fffu + ((ua >> 16) & 1u);   // RNE
    ub += 0x7fffu + ((ub >> 16) & 1u);
    return (ua >> 16) | (ub & 0xffff0000u);
}

__device__ __forceinline__ float2 unpack_bf16(unsigned w) {
    float2 r;
    r.x = __uint_as_float(w << 16);
    r.y = __uint_as_float(w & 0xffff0000u);
    return r;
}

__global__ void zero_int_kernel(int* __restrict__ p, int n) {
    int i = blockIdx.x * blockDim.x + threadIdx.x;
    if (i < n) p[i] = 0;
}

// fused histogram over both COO row lists
__global__ void hist2_kernel(const int* __restrict__ rows_p, const int* __restrict__ rows_m,
                             int E, int* __restrict__ cnt) {
    int e = blockIdx.x * blockDim.x + threadIdx.x;
    if (e < 2 * E) {
        int r = (e < E) ? rows_p[e] : rows_m[e - E];
        atomicAdd(&cnt[r], 1);
    }
}

// --- 3-phase parallel exclusive scan (safe unconditional shuffles) ---
__global__ void scanA_kernel(const int* __restrict__ cnt, int* __restrict__ bsum, int n) {
    __shared__ int wsum[16];
    int tid = threadIdx.x, lane = tid & 63, wid = tid >> 6;
    int i = blockIdx.x * 1024 + tid;
    int x = (i < n) ? cnt[i] : 0;
#pragma unroll
    for (int o = 1; o < 64; o <<= 1) { int y = __shfl_up(x, o); if (lane >= o) x += y; }
    if (lane == 63) wsum[wid] = x;
    __syncthreads();
    if (tid == 0) {
        int s = 0;
#pragma unroll
        for (int w = 0; w < 16; ++w) s += wsum[w];
        bsum[blockIdx.x] = s;
    }
}

__global__ void scanB_kernel(int* __restrict__ bsum, int nb) {
    __shared__ int wsum[16];
    int tid = threadIdx.x, lane = tid & 63, wid = tid >> 6;
    int x = (tid < nb) ? bsum[tid] : 0;
    int incl = x;
#pragma unroll
    for (int o = 1; o < 64; o <<= 1) { int y = __shfl_up(incl, o); if (lane >= o) incl += y; }
    if (lane == 63) wsum[wid] = incl;
    __syncthreads();
    if (wid == 0) {
        int s = (lane < 16) ? wsum[lane] : 0;
#pragma unroll
        for (int o = 1; o < 16; o <<= 1) { int y = __shfl_up(s, o); if (lane >= o) s += y; }
        if (lane < 16) wsum[lane] = s;
    }
    __syncthreads();
    int base = (wid > 0) ? wsum[wid - 1] : 0;
    if (tid < nb) bsum[tid] = base + incl - x;
}

// writes off[] AND cur[] (cursor copy for fill)
__global__ void scanC_kernel(const int* __restrict__ cnt, const int* __restrict__ bsum,
                             int* __restrict__ off, int* __restrict__ cur, int n) {
    __shared__ int wsum[16];
    int tid = threadIdx.x, lane = tid & 63, wid = tid >> 6;
    int i = blockIdx.x * 1024 + tid;
    int x = (i < n) ? cnt[i] : 0;
    int incl = x;
#pragma unroll
    for (int o = 1; o < 64; o <<= 1) { int y = __shfl_up(incl, o); if (lane >= o) incl += y; }
    if (lane == 63) wsum[wid] = incl;
    __syncthreads();
    if (wid == 0) {
        int s = (lane < 16) ? wsum[lane] : 0;
#pragma unroll
        for (int o = 1; o < 16; o <<= 1) { int y = __shfl_up(s, o); if (lane >= o) s += y; }
        if (lane < 16) wsum[lane] = s;
    }
    __syncthreads();
    int base = bsum[blockIdx.x] + ((wid > 0) ? wsum[wid - 1] : 0);
    if (i < n) {
        int ex = base + incl - x;
        off[i] = ex;
        cur[i] = ex;
        if (i == n - 1) off[n] = base + incl;
    }
}

// fused fill of merged CSR: packed (col, signed val) int2 edges.
__global__ void fill2_kernel(const int* __restrict__ rows_p, const int* __restrict__ cols_p,
                             const float* __restrict__ vals_p,
                             const int* __restrict__ rows_m, const int* __restrict__ cols_m,
                             const float* __restrict__ vals_m, int E,
                             int* __restrict__ cur, int2* __restrict__ edge) {
    int e = blockIdx.x * blockDim.x + threadIdx.x;
    if (e < 2 * E) {
        int r, c; float v;
        if (e < E) { r = rows_p[e]; c = cols_p[e]; v =  vals_p[e]; }
        else       { r = rows_m[e - E]; c = cols_m[e - E]; v = -vals_m[e - E]; }
        int p = atomicAdd(&cur[r], 1);
        edge[p] = make_int2(c, __float_as_int(v));
    }
}

// Sb = bf16(X+M0), Db = bf16(X-M0), tXb = bf16(0.15*X). n = ND/2 pairs.
__global__ void init_kernel(const float* __restrict__ X, const float* __restrict__ M0,
                            unsigned* __restrict__ Sb, unsigned* __restrict__ Db,
                            unsigned* __restrict__ tXb, int n) {
    int i = blockIdx.x * blockDim.x + threadIdx.x;
    if (i < n) {
        float2 x = ((const float2*)X)[i];
        float2 m = ((const float2*)M0)[i];
        Sb[i]  = pack_bf16(x.x + m.x, x.y + m.y);
        Db[i]  = pack_bf16(x.x - m.x, x.y - m.y);
        tXb[i] = pack_bf16(0.15f * x.x, 0.15f * x.y);
    }
}

// P = (S+D)/2, M = (S-D)/2 -> fp32 d_out. n = ND/2 pairs.
__global__ void final_kernel(const unsigned* __restrict__ Sb, const unsigned* __restrict__ Db,
                             float* __restrict__ P, float* __restrict__ M, int n) {
    int i = blockIdx.x * blockDim.x + threadIdx.x;
    if (i < n) {
        float2 s = unpack_bf16(Sb[i]);
        float2 d = unpack_bf16(Db[i]);
        ((float2*)P)[i] = make_float2(0.5f * (s.x + d.x), 0.5f * (s.y + d.y));
        ((float2*)M)[i] = make_float2(0.5f * (s.x - d.x), 0.5f * (s.y - d.y));
    }
}

// 1D grid with XCD-partition swizzle. Block b: slot=b&7; sys=slot>>2
// (0:S on XCD 0-3, 1:D on XCD 4-7); r4=(b>>3)*4+(slot&3) indexes a
// 4-row group within the system. One wave per row, lane = 2 features.
__global__ __launch_bounds__(TB) void layer_kernel(
    const int* __restrict__ off, const int2* __restrict__ edge,
    const unsigned* __restrict__ Sin, const unsigned* __restrict__ Din,
    unsigned* __restrict__ Sout, unsigned* __restrict__ Dout,
    const unsigned* __restrict__ tXb, int N) {
    int b = blockIdx.x;
    int slot = b & 7;
    int sys = slot >> 2;
    int r4 = (b >> 3) * 4 + (slot & 3);
    int row = r4 * 4 + (threadIdx.x >> 6);
    if (row >= N) return;
    int lane = threadIdx.x & 63;
    const unsigned* __restrict__ In  = sys ? Din : Sin;
    unsigned* __restrict__       Out = sys ? Dout : Sout;

    int ridx = row * 64 + lane;
    float2 t = unpack_bf16(tXb[ridx]);
    float ax = t.x, ay = t.y;

    int bg = off[row], e = off[row + 1];
    int j = bg;
    for (; j + 8 <= e; j += 8) {
        int2 e0 = edge[j],     e1 = edge[j + 1], e2 = edge[j + 2], e3 = edge[j + 3];
        int2 e4 = edge[j + 4], e5 = edge[j + 5], e6 = edge[j + 6], e7 = edge[j + 7];
        unsigned w0 = In[e0.x * 64 + lane];
        unsigned w1 = In[e1.x * 64 + lane];
        unsigned w2 = In[e2.x * 64 + lane];
        unsigned w3 = In[e3.x * 64 + lane];
        unsigned w4 = In[e4.x * 64 + lane];
        unsigned w5 = In[e5.x * 64 + lane];
        unsigned w6 = In[e6.x * 64 + lane];
        unsigned w7 = In[e7.x * 64 + lane];
        float v0 = __int_as_float(e0.y), v1 = __int_as_float(e1.y);
        float v2 = __int_as_float(e2.y), v3 = __int_as_float(e3.y);
        float v4 = __int_as_float(e4.y), v5 = __int_as_float(e5.y);
        float v6 = __int_as_float(e6.y), v7 = __int_as_float(e7.y);
        if (!sys) {
            v0 = fabsf(v0); v1 = fabsf(v1); v2 = fabsf(v2); v3 = fabsf(v3);
            v4 = fabsf(v4); v5 = fabsf(v5); v6 = fabsf(v6); v7 = fabsf(v7);
        }
        float2 g0 = unpack_bf16(w0), g1 = unpack_bf16(w1);
        float2 g2 = unpack_bf16(w2), g3 = unpack_bf16(w3);
        float2 g4 = unpack_bf16(w4), g5 = unpack_bf16(w5);
        float2 g6 = unpack_bf16(w6), g7 = unpack_bf16(w7);
        ax += v0 * g0.x + v1 * g1.x + v2 * g2.x + v3 * g3.x
            + v4 * g4.x + v5 * g5.x + v6 * g6.x + v7 * g7.x;
        ay += v0 * g0.y + v1 * g1.y + v2 * g2.y + v3 * g3.y
            + v4 * g4.y + v5 * g5.y + v6 * g6.y + v7 * g7.y;
    }
    for (; j < e; ++j) {
        int2 ed = edge[j];
        float v = __int_as_float(ed.y);
        if (!sys) v = fabsf(v);
        float2 g = unpack_bf16(In[ed.x * 64 + lane]);
        ax += v * g.x;
        ay += v * g.y;
    }
    Out[ridx] = pack_bf16(ax, ay);
}

extern "C" void kernel_launch(void* const* d_in, const int* in_sizes, int n_in,
                              void* d_out, int out_size, void* d_ws, size_t ws_size,
                              hipStream_t stream) {
    const int*   rows_p = (const int*)d_in[0];
    const int*   cols_p = (const int*)d_in[1];
    const float* vals_p = (const float*)d_in[2];
    const int*   rows_m = (const int*)d_in[3];
    const int*   cols_m = (const int*)d_in[4];
    const float* vals_m = (const float*)d_in[5];
    const float* X      = (const float*)d_in[6];
    const float* M0     = (const float*)d_in[7];

    const int E = in_sizes[0];
    const int D = 128;
    const int N = in_sizes[6] / D;
    const int K = 10;
    const int E2 = 2 * E;
    const size_t ND = (size_t)N * D;
    const int NP = (int)(ND / 2);   // packed bf16 pairs

    float* outP = (float*)d_out;
    float* outM = outP + ND;

    char* ws = (char*)d_ws;
    size_t o = 0;
    auto alloc = [&](size_t b) -> void* {
        void* p = ws + o;
        o += (b + 255) & ~(size_t)255;
        return p;
    };
    unsigned* SbA  = (unsigned*)alloc((size_t)NP * 4);
    unsigned* DbA  = (unsigned*)alloc((size_t)NP * 4);
    unsigned* SbB  = (unsigned*)alloc((size_t)NP * 4);
    unsigned* DbB  = (unsigned*)alloc((size_t)NP * 4);
    unsigned* tXb  = (unsigned*)alloc((size_t)NP * 4);
    int*      cnt  = (int*)alloc((size_t)N * sizeof(int));
    int*      off  = (int*)alloc((size_t)(N + 1) * sizeof(int));
    int*      cur  = (int*)alloc((size_t)N * sizeof(int));
    int*      bsum = (int*)alloc(1024 * sizeof(int));
    int2*     edge = (int2*)alloc((size_t)E2 * sizeof(int2));

    int gN  = (N + TB - 1) / TB;
    int gE2 = (E2 + TB - 1) / TB;
    int gNP = (NP + TB - 1) / TB;
    int nb  = (N + 1023) / 1024;

    // --- build merged CSR ---
    zero_int_kernel<<<gN, TB, 0, stream>>>(cnt, N);
    hist2_kernel<<<gE2, TB, 0, stream>>>(rows_p, rows_m, E, cnt);
    scanA_kernel<<<nb, 1024, 0, stream>>>(cnt, bsum, N);
    scanB_kernel<<<1, 1024, 0, stream>>>(bsum, nb);
    scanC_kernel<<<nb, 1024, 0, stream>>>(cnt, bsum, off, cur, N);
    fill2_kernel<<<gE2, TB, 0, stream>>>(rows_p, cols_p, vals_p,
                                         rows_m, cols_m, vals_m, E, cur, edge);

    // --- init bf16 states ---
    init_kernel<<<gNP, TB, 0, stream>>>(X, M0, SbA, DbA, tXb, NP);

    // --- K layers, ping-pong; 1D swizzled grid covering both systems ---
    int blocks_per_sys = (N + 3) / 4;               // 4 rows per block
    int gridx = ((blocks_per_sys + 3) / 4) * 8;     // pad to full 8-block chunks
    unsigned *Si = SbA, *Di = DbA, *So = SbB, *Do = DbB;
    for (int k = 0; k < K; ++k) {
        layer_kernel<<<gridx, TB, 0, stream>>>(off, edge, Si, Di, So, Do, tXb, N);
        unsigned* t;
        t = Si; Si = So; So = t;
        t = Di; Di = Do; Do = t;
    }

    // --- unpack to fp32 outputs ---
    final_kernel<<<gNP, TB, 0, stream>>>(Si, Di, outP, outM, NP);
}

// Round 7
// 1086.980 us; speedup vs baseline: 1.9169x; 1.0652x over previous
//
#include <hip/hip_runtime.h>
#include <math.h>

// SidNet signed diffusion, S/D-decoupled + bf16 state, INTERLEAVED layout:
//   row r state = [S_r (128 bf16) | D_r (128 bf16)] = 512B.
//   S' = (Ap+Am)@S + cX  (lanes 0-31, |v|) ; D' = (Ap-Am)@D + cX (lanes 32-63, v)
// One wave per row; each edge = ONE 64-lane x 8B gather (512B) serving both
// systems. No shuffles, no partial writes, no XCD-mapping assumptions.
// CSR build identical to round 5 (proven under graph replay).

#define TB 256

__device__ __forceinline__ unsigned pack_bf16(float a, float b) {
    unsigned ua = __float_as_uint(a), ub = __float_as_uint(b);
    ua += 0x7fffu + ((ua >> 16) & 1u);   // RNE
    ub += 0x7fffu + ((ub >> 16) & 1u);
    return (ua >> 16) | (ub & 0xffff0000u);
}

__device__ __forceinline__ float2 unpack_bf16(unsigned w) {
    float2 r;
    r.x = __uint_as_float(w << 16);
    r.y = __uint_as_float(w & 0xffff0000u);
    return r;
}

__global__ void zero_int_kernel(int* __restrict__ p, int n) {
    int i = blockIdx.x * blockDim.x + threadIdx.x;
    if (i < n) p[i] = 0;
}

// fused histogram over both COO row lists (round-5 proven)
__global__ void hist2_kernel(const int* __restrict__ rows_p, const int* __restrict__ rows_m,
                             int E, int* __restrict__ cnt) {
    int e = blockIdx.x * blockDim.x + threadIdx.x;
    if (e < 2 * E) {
        int r = (e < E) ? rows_p[e] : rows_m[e - E];
        atomicAdd(&cnt[r], 1);
    }
}

// --- 3-phase parallel exclusive scan (safe unconditional shuffles) ---
__global__ void scanA_kernel(const int* __restrict__ cnt, int* __restrict__ bsum, int n) {
    __shared__ int wsum[16];
    int tid = threadIdx.x, lane = tid & 63, wid = tid >> 6;
    int i = blockIdx.x * 1024 + tid;
    int x = (i < n) ? cnt[i] : 0;
#pragma unroll
    for (int o = 1; o < 64; o <<= 1) { int y = __shfl_up(x, o); if (lane >= o) x += y; }
    if (lane == 63) wsum[wid] = x;
    __syncthreads();
    if (tid == 0) {
        int s = 0;
#pragma unroll
        for (int w = 0; w < 16; ++w) s += wsum[w];
        bsum[blockIdx.x] = s;
    }
}

__global__ void scanB_kernel(int* __restrict__ bsum, int nb) {
    __shared__ int wsum[16];
    int tid = threadIdx.x, lane = tid & 63, wid = tid >> 6;
    int x = (tid < nb) ? bsum[tid] : 0;
    int incl = x;
#pragma unroll
    for (int o = 1; o < 64; o <<= 1) { int y = __shfl_up(incl, o); if (lane >= o) incl += y; }
    if (lane == 63) wsum[wid] = incl;
    __syncthreads();
    if (wid == 0) {
        int s = (lane < 16) ? wsum[lane] : 0;
#pragma unroll
        for (int o = 1; o < 16; o <<= 1) { int y = __shfl_up(s, o); if (lane >= o) s += y; }
        if (lane < 16) wsum[lane] = s;
    }
    __syncthreads();
    int base = (wid > 0) ? wsum[wid - 1] : 0;
    if (tid < nb) bsum[tid] = base + incl - x;
}

__global__ void scanC_kernel(const int* __restrict__ cnt, const int* __restrict__ bsum,
                             int* __restrict__ off, int* __restrict__ cur, int n) {
    __shared__ int wsum[16];
    int tid = threadIdx.x, lane = tid & 63, wid = tid >> 6;
    int i = blockIdx.x * 1024 + tid;
    int x = (i < n) ? cnt[i] : 0;
    int incl = x;
#pragma unroll
    for (int o = 1; o < 64; o <<= 1) { int y = __shfl_up(incl, o); if (lane >= o) incl += y; }
    if (lane == 63) wsum[wid] = incl;
    __syncthreads();
    if (wid == 0) {
        int s = (lane < 16) ? wsum[lane] : 0;
#pragma unroll
        for (int o = 1; o < 16; o <<= 1) { int y = __shfl_up(s, o); if (lane >= o) s += y; }
        if (lane < 16) wsum[lane] = s;
    }
    __syncthreads();
    int base = bsum[blockIdx.x] + ((wid > 0) ? wsum[wid - 1] : 0);
    if (i < n) {
        int ex = base + incl - x;
        off[i] = ex;
        cur[i] = ex;
        if (i == n - 1) off[n] = base + incl;
    }
}

// fused fill of merged CSR: packed (col, signed val) int2 edges (round-5 proven)
__global__ void fill2_kernel(const int* __restrict__ rows_p, const int* __restrict__ cols_p,
                             const float* __restrict__ vals_p,
                             const int* __restrict__ rows_m, const int* __restrict__ cols_m,
                             const float* __restrict__ vals_m, int E,
                             int* __restrict__ cur, int2* __restrict__ edge) {
    int e = blockIdx.x * blockDim.x + threadIdx.x;
    if (e < 2 * E) {
        int r, c; float v;
        if (e < E) { r = rows_p[e]; c = cols_p[e]; v =  vals_p[e]; }
        else       { r = rows_m[e - E]; c = cols_m[e - E]; v = -vals_m[e - E]; }
        int p = atomicAdd(&cur[r], 1);
        edge[p] = make_int2(c, __float_as_int(v));
    }
}

// Interleaved init: thread i covers row r=i>>5, quad q=i&31 (features 4q..4q+3).
// SD[r*64+q]    = bf16x4 of S0 = X+M0
// SD[r*64+32+q] = bf16x4 of D0 = X-M0
// tXb[r*32+q]   = bf16x4 of 0.15*X
__global__ void init_kernel(const float* __restrict__ X, const float* __restrict__ M0,
                            uint2* __restrict__ SD, uint2* __restrict__ tXb, int n32) {
    int i = blockIdx.x * blockDim.x + threadIdx.x;
    if (i < n32) {
        int r = i >> 5, q = i & 31;
        float4 x = ((const float4*)X)[(size_t)r * 32 + q];
        float4 m = ((const float4*)M0)[(size_t)r * 32 + q];
        SD[(size_t)r * 64 + q]      = make_uint2(pack_bf16(x.x + m.x, x.y + m.y),
                                                 pack_bf16(x.z + m.z, x.w + m.w));
        SD[(size_t)r * 64 + 32 + q] = make_uint2(pack_bf16(x.x - m.x, x.y - m.y),
                                                 pack_bf16(x.z - m.z, x.w - m.w));
        tXb[(size_t)r * 32 + q]     = make_uint2(pack_bf16(0.15f * x.x, 0.15f * x.y),
                                                 pack_bf16(0.15f * x.z, 0.15f * x.w));
    }
}

// P = (S+D)/2, M = (S-D)/2 -> fp32 d_out.
__global__ void final_kernel(const uint2* __restrict__ SD,
                             float* __restrict__ P, float* __restrict__ M, int n32) {
    int i = blockIdx.x * blockDim.x + threadIdx.x;
    if (i < n32) {
        int r = i >> 5, q = i & 31;
        uint2 ws = SD[(size_t)r * 64 + q];
        uint2 wd = SD[(size_t)r * 64 + 32 + q];
        float2 s0 = unpack_bf16(ws.x), s1 = unpack_bf16(ws.y);
        float2 d0 = unpack_bf16(wd.x), d1 = unpack_bf16(wd.y);
        float4 p4 = make_float4(0.5f * (s0.x + d0.x), 0.5f * (s0.y + d0.y),
                                0.5f * (s1.x + d1.x), 0.5f * (s1.y + d1.y));
        float4 m4 = make_float4(0.5f * (s0.x - d0.x), 0.5f * (s0.y - d0.y),
                                0.5f * (s1.x - d1.x), 0.5f * (s1.y - d1.y));
        ((float4*)P)[(size_t)r * 32 + q] = p4;
        ((float4*)M)[(size_t)r * 32 + q] = m4;
    }
}

// One wave per row. lane<32: S-system features 4*lane..; lane>=32: D-system.
// Each edge: one uint2 gather (512B across the wave) serves both systems.
__global__ __launch_bounds__(TB) void layer_kernel(
    const int* __restrict__ off, const int2* __restrict__ edge,
    const uint2* __restrict__ In, uint2* __restrict__ Out,
    const uint2* __restrict__ tXb, int N) {
    int row = blockIdx.x * 4 + (threadIdx.x >> 6);
    if (row >= N) return;
    int lane = threadIdx.x & 63;
    int sel = lane >> 5;              // 0: S-half (|v|), 1: D-half (signed v)
    int q = lane & 31;

    uint2 t = tXb[(size_t)row * 32 + q];
    float2 t0 = unpack_bf16(t.x), t1 = unpack_bf16(t.y);
    float a0 = t0.x, a1 = t0.y, a2 = t1.x, a3 = t1.y;

    int bg = off[row], e = off[row + 1];
    int j = bg;
    for (; j + 4 <= e; j += 4) {
        int2 e0 = edge[j], e1 = edge[j + 1], e2 = edge[j + 2], e3 = edge[j + 3];
        uint2 w0 = In[(size_t)e0.x * 64 + lane];
        uint2 w1 = In[(size_t)e1.x * 64 + lane];
        uint2 w2 = In[(size_t)e2.x * 64 + lane];
        uint2 w3 = In[(size_t)e3.x * 64 + lane];
        float v0 = __int_as_float(e0.y), v1 = __int_as_float(e1.y);
        float v2 = __int_as_float(e2.y), v3 = __int_as_float(e3.y);
        if (!sel) { v0 = fabsf(v0); v1 = fabsf(v1); v2 = fabsf(v2); v3 = fabsf(v3); }
        float2 g0a = unpack_bf16(w0.x), g0b = unpack_bf16(w0.y);
        float2 g1a = unpack_bf16(w1.x), g1b = unpack_bf16(w1.y);
        float2 g2a = unpack_bf16(w2.x), g2b = unpack_bf16(w2.y);
        float2 g3a = unpack_bf16(w3.x), g3b = unpack_bf16(w3.y);
        a0 += v0 * g0a.x + v1 * g1a.x + v2 * g2a.x + v3 * g3a.x;
        a1 += v0 * g0a.y + v1 * g1a.y + v2 * g2a.y + v3 * g3a.y;
        a2 += v0 * g0b.x + v1 * g1b.x + v2 * g2b.x + v3 * g3b.x;
        a3 += v0 * g0b.y + v1 * g1b.y + v2 * g2b.y + v3 * g3b.y;
    }
    for (; j < e; ++j) {
        int2 ed = edge[j];
        uint2 w = In[(size_t)ed.x * 64 + lane];
        float v = __int_as_float(ed.y);
        if (!sel) v = fabsf(v);
        float2 ga = unpack_bf16(w.x), gb = unpack_bf16(w.y);
        a0 += v * ga.x; a1 += v * ga.y; a2 += v * gb.x; a3 += v * gb.y;
    }
    Out[(size_t)row * 64 + lane] = make_uint2(pack_bf16(a0, a1), pack_bf16(a2, a3));
}

extern "C" void kernel_launch(void* const* d_in, const int* in_sizes, int n_in,
                              void* d_out, int out_size, void* d_ws, size_t ws_size,
                              hipStream_t stream) {
    const int*   rows_p = (const int*)d_in[0];
    const int*   cols_p = (const int*)d_in[1];
    const float* vals_p = (const float*)d_in[2];
    const int*   rows_m = (const int*)d_in[3];
    const int*   cols_m = (const int*)d_in[4];
    const float* vals_m = (const float*)d_in[5];
    const float* X      = (const float*)d_in[6];
    const float* M0     = (const float*)d_in[7];

    const int E = in_sizes[0];
    const int D = 128;
    const int N = in_sizes[6] / D;
    const int K = 10;
    const int E2 = 2 * E;
    const size_t ND = (size_t)N * D;
    const int N32 = N * 32;             // quads per (row set)

    float* outP = (float*)d_out;
    float* outM = outP + ND;

    char* ws = (char*)d_ws;
    size_t o = 0;
    auto alloc = [&](size_t b) -> void* {
        void* p = ws + o;
        o += (b + 255) & ~(size_t)255;
        return p;
    };
    uint2* SDA  = (uint2*)alloc((size_t)N * 64 * 8);   // 25.6 MB
    uint2* SDB  = (uint2*)alloc((size_t)N * 64 * 8);   // 25.6 MB
    uint2* tXb  = (uint2*)alloc((size_t)N * 32 * 8);   // 12.8 MB
    int*   cnt  = (int*)alloc((size_t)N * sizeof(int));
    int*   off  = (int*)alloc((size_t)(N + 1) * sizeof(int));
    int*   cur  = (int*)alloc((size_t)N * sizeof(int));
    int*   bsum = (int*)alloc(1024 * sizeof(int));
    int2*  edge = (int2*)alloc((size_t)E2 * sizeof(int2));  // 9.6 MB

    int gN   = (N + TB - 1) / TB;
    int gE2  = (E2 + TB - 1) / TB;
    int gN32 = (N32 + TB - 1) / TB;
    int nb   = (N + 1023) / 1024;

    // --- build merged CSR (round-5 proven path) ---
    zero_int_kernel<<<gN, TB, 0, stream>>>(cnt, N);
    hist2_kernel<<<gE2, TB, 0, stream>>>(rows_p, rows_m, E, cnt);
    scanA_kernel<<<nb, 1024, 0, stream>>>(cnt, bsum, N);
    scanB_kernel<<<1, 1024, 0, stream>>>(bsum, nb);
    scanC_kernel<<<nb, 1024, 0, stream>>>(cnt, bsum, off, cur, N);
    fill2_kernel<<<gE2, TB, 0, stream>>>(rows_p, cols_p, vals_p,
                                         rows_m, cols_m, vals_m, E, cur, edge);

    // --- init interleaved bf16 state ---
    init_kernel<<<gN32, TB, 0, stream>>>(X, M0, SDA, tXb, N32);

    // --- K layers, ping-pong; K even -> final state lands in SDA ---
    int gL = (N + 3) / 4;
    uint2 *Si = SDA, *So = SDB;
    for (int k = 0; k < K; ++k) {
        layer_kernel<<<gL, TB, 0, stream>>>(off, edge, Si, So, tXb, N);
        uint2* t = Si; Si = So; So = t;
    }

    // --- unpack to fp32 outputs ---
    final_kernel<<<gN32, TB, 0, stream>>>(Si, outP, outM, N32);
}